// Round 1
// baseline (1466.878 us; speedup 1.0000x reference)
//
#include <hip/hip_runtime.h>
#include <stdint.h>
#include <math.h>

// Problem dims
#define T_ 4
#define B_ 8
#define C_ 256
#define N_ 2048
#define TB_ 32          // T_*B_
#define H_ 16
#define D_ 16
#define NTOT 65536      // T_*B_*N_  (BN reduction count per channel)
#define EPS 1e-5

// ---------------------------------------------------------------------------
// X-tile loader: float input (x, y) or uint8 input (binary spikes s)
// ---------------------------------------------------------------------------
template <typename XT>
__device__ inline float4 load_x4(const XT* p);
template <>
__device__ inline float4 load_x4<float>(const float* p) { return *(const float4*)p; }
template <>
__device__ inline float4 load_x4<uint8_t>(const uint8_t* p) {
  uchar4 u = *(const uchar4*)p;
  return make_float4((float)u.x, (float)u.y, (float)u.z, (float)u.w);
}

// ---------------------------------------------------------------------------
// conv1x1 as GEMM with fp64 accumulation:
//   H[tb][o][n] = sum_c W[o][c] * X[tb][c][n]
// Products of fp32 values are EXACT in fp64 (24+24 < 53 mantissa bits), so
// the dot is correct to ~1e-16 rel — binary spike decisions then match a
// float64 reference with probability ~1 (flip window ~1e-13).
// Block: 256 threads, 64(o) x 64(n) tile, BK=16, 4x4 fp64 accs per thread.
// Grid: (N/64=32, C/64=4, TB=32)
// ---------------------------------------------------------------------------
template <typename XT>
__global__ __launch_bounds__(256) void conv_gemm(const float* __restrict__ W,
                                                 const XT* __restrict__ X,
                                                 double* __restrict__ Hout) {
  __shared__ float As[16][64];   // As[c_local][o_local]
  __shared__ float Bs[16][64];   // Bs[c_local][n_local]
  const int n0 = blockIdx.x * 64;
  const int o0 = blockIdx.y * 64;
  const int tb = blockIdx.z;
  const int tid = (int)threadIdx.x;
  const int ty = tid >> 4;       // 0..15  (o quad)
  const int tx = tid & 15;       // 0..15  (n quad)
  const int arow = tid >> 2;     // 0..63  (o for A load)
  const int af4  = tid & 3;      // float4 index along c
  const int brow = tid >> 4;     // 0..15  (c for B load)
  const int bcol = tid & 15;     // float4 index along n

  double acc[4][4] = {};

  for (int c0 = 0; c0 < C_; c0 += 16) {
    const float4 w4 = *(const float4*)(W + (size_t)(o0 + arow) * C_ + c0 + af4 * 4);
    const float4 xv = load_x4<XT>(X + ((size_t)(tb * C_ + c0 + brow)) * N_ + n0 + bcol * 4);
    As[af4 * 4 + 0][arow] = w4.x;
    As[af4 * 4 + 1][arow] = w4.y;
    As[af4 * 4 + 2][arow] = w4.z;
    As[af4 * 4 + 3][arow] = w4.w;
    *(float4*)&Bs[brow][bcol * 4] = xv;
    __syncthreads();
#pragma unroll
    for (int kk = 0; kk < 16; ++kk) {
      const float4 av = *(const float4*)&As[kk][ty * 4];
      const float4 bv = *(const float4*)&Bs[kk][tx * 4];
      const double a[4] = {(double)av.x, (double)av.y, (double)av.z, (double)av.w};
      const double b[4] = {(double)bv.x, (double)bv.y, (double)bv.z, (double)bv.w};
#pragma unroll
      for (int i = 0; i < 4; ++i)
#pragma unroll
        for (int j = 0; j < 4; ++j) acc[i][j] += a[i] * b[j];
    }
    __syncthreads();
  }
#pragma unroll
  for (int i = 0; i < 4; ++i) {
    double* dst = Hout + ((size_t)(tb * C_ + o0 + ty * 4 + i)) * N_ + n0 + tx * 4;
    dst[0] = acc[i][0];
    dst[1] = acc[i][1];
    dst[2] = acc[i][2];
    dst[3] = acc[i][3];
  }
}

// ---------------------------------------------------------------------------
// Per-channel BN statistics over (T,B,N): one block per channel, fp64.
// Writes mean[c] and invstd[c] = 1/sqrt(var + eps).
// ---------------------------------------------------------------------------
__global__ __launch_bounds__(256) void stats_kernel(const double* __restrict__ Hh,
                                                    double* __restrict__ mean,
                                                    double* __restrict__ invstd) {
  __shared__ double ssum[256];
  __shared__ double ssq[256];
  const int o = blockIdx.x;
  const int tid = (int)threadIdx.x;
  double s = 0.0, q = 0.0;
  for (int tb = 0; tb < TB_; ++tb) {
    const double* row = Hh + ((size_t)(tb * C_ + o)) * N_;
    for (int n = tid; n < N_; n += 256) {
      const double v = row[n];
      s += v;
      q += v * v;
    }
  }
  ssum[tid] = s;
  ssq[tid] = q;
  __syncthreads();
  for (int st = 128; st > 0; st >>= 1) {
    if (tid < st) {
      ssum[tid] += ssum[tid + st];
      ssq[tid] += ssq[tid + st];
    }
    __syncthreads();
  }
  if (tid == 0) {
    const double m = ssum[0] / (double)NTOT;
    const double var = ssq[0] / (double)NTOT - m * m;
    mean[o] = m;
    invstd[o] = 1.0 / sqrt(var + EPS);
  }
}

// ---------------------------------------------------------------------------
// BN-normalize + spike (>= 1.0). OT = uint8_t for intermediate spike maps,
// float for the final output.
// ---------------------------------------------------------------------------
template <typename OT>
__global__ __launch_bounds__(256) void spike_kernel(const double* __restrict__ Hh,
                                                    const float* __restrict__ gamma,
                                                    const float* __restrict__ beta,
                                                    const double* __restrict__ mean,
                                                    const double* __restrict__ invstd,
                                                    OT* __restrict__ out) {
  const size_t idx = (size_t)blockIdx.x * 256 + threadIdx.x;
  const int c = (int)((idx >> 11) & 255);  // N_=2048 -> channel index
  const double v =
      (double)gamma[c] * (Hh[idx] - mean[c]) * invstd[c] + (double)beta[c];
  out[idx] = (OT)(v >= 1.0 ? 1 : 0);
}

// ---------------------------------------------------------------------------
// Linear attention, all-binary operands -> exact integer arithmetic.
// One block per (tb, h). Phase 1: kv[d][e] = sum_n K[d][n]&V[e][n] via
// popcount on 4-byte groups (bytes are 0/1). Phase 2: o[e][n] =
// 0.25 * sum_d Q[d][n]*kv[d][e]; spike at 0.5 (exact: multiples of 0.25).
// ---------------------------------------------------------------------------
__global__ __launch_bounds__(256) void attn_kernel(const uint8_t* __restrict__ Sq,
                                                   const uint8_t* __restrict__ Sk,
                                                   const uint8_t* __restrict__ Sv,
                                                   uint8_t* __restrict__ Sout) {
  __shared__ float kvs[16][17];
  const int tb = (int)blockIdx.x >> 4;
  const int h = (int)blockIdx.x & 15;
  const size_t base = ((size_t)(tb * C_ + h * D_)) * N_;
  const int tid = (int)threadIdx.x;
  {
    const int d = tid >> 4, e = tid & 15;
    const uint32_t* kr = (const uint32_t*)(Sk + base + (size_t)d * N_);
    const uint32_t* vr = (const uint32_t*)(Sv + base + (size_t)e * N_);
    int cnt = 0;
    for (int i = 0; i < N_ / 4; ++i) cnt += __popc(kr[i] & vr[i]);
    kvs[d][e] = (float)cnt;
  }
  __syncthreads();
  for (int rep = 0; rep < 8; ++rep) {
    const int n = rep * 256 + tid;
    float qv[16];
#pragma unroll
    for (int d = 0; d < 16; ++d) qv[d] = (float)Sq[base + (size_t)d * N_ + n];
#pragma unroll
    for (int e = 0; e < 16; ++e) {
      float acc = 0.f;
#pragma unroll
      for (int d = 0; d < 16; ++d) acc += qv[d] * kvs[d][e];
      Sout[base + (size_t)e * N_ + n] = (0.25f * acc >= 0.5f) ? (uint8_t)1 : (uint8_t)0;
    }
  }
}

// ---------------------------------------------------------------------------
// Launcher. ws layout (bytes):
//   [0,            134217728)  h64      : double[16M]   (reused by all 4 convs)
//   [134217728,    151 M     )  Sq u8[16M]
//   [+16M]                      Sk u8[16M]
//   [+16M]                      Sv u8[16M]
//   [+16M]                      Sbuf u8[16M]  (attention output spikes)
//   then double mean[256], invstd[256]
// total ~192 MB.
// ---------------------------------------------------------------------------
extern "C" void kernel_launch(void* const* d_in, const int* in_sizes, int n_in,
                              void* d_out, int out_size, void* d_ws, size_t ws_size,
                              hipStream_t stream) {
  const float* x      = (const float*)d_in[0];
  const float* y      = (const float*)d_in[1];
  const float* q_w    = (const float*)d_in[2];
  const float* q_g    = (const float*)d_in[3];
  const float* q_b    = (const float*)d_in[4];
  const float* k_w    = (const float*)d_in[5];
  const float* k_g    = (const float*)d_in[6];
  const float* k_b    = (const float*)d_in[7];
  const float* v_w    = (const float*)d_in[8];
  const float* v_g    = (const float*)d_in[9];
  const float* v_b    = (const float*)d_in[10];
  const float* p_w    = (const float*)d_in[11];
  const float* p_g    = (const float*)d_in[12];
  const float* p_b    = (const float*)d_in[13];
  float* out = (float*)d_out;

  char* ws = (char*)d_ws;
  const size_t NE = (size_t)TB_ * C_ * N_;  // 16,777,216
  double* h64   = (double*)ws;
  uint8_t* Sq   = (uint8_t*)(ws + NE * 8);
  uint8_t* Sk   = Sq + NE;
  uint8_t* Sv   = Sk + NE;
  uint8_t* Sbuf = Sv + NE;
  double* mean   = (double*)(Sbuf + NE);
  double* invstd = mean + C_;

  const dim3 gridG(N_ / 64, C_ / 64, TB_);  // 32,4,32
  const dim3 blk(256);
  const int spikeBlocks = (int)(NE / 256);  // 65536

  // --- Q from x ---
  conv_gemm<float><<<gridG, blk, 0, stream>>>(q_w, x, h64);
  stats_kernel<<<C_, blk, 0, stream>>>(h64, mean, invstd);
  spike_kernel<uint8_t><<<spikeBlocks, blk, 0, stream>>>(h64, q_g, q_b, mean, invstd, Sq);
  // --- K from y ---
  conv_gemm<float><<<gridG, blk, 0, stream>>>(k_w, y, h64);
  stats_kernel<<<C_, blk, 0, stream>>>(h64, mean, invstd);
  spike_kernel<uint8_t><<<spikeBlocks, blk, 0, stream>>>(h64, k_g, k_b, mean, invstd, Sk);
  // --- V from y ---
  conv_gemm<float><<<gridG, blk, 0, stream>>>(v_w, y, h64);
  stats_kernel<<<C_, blk, 0, stream>>>(h64, mean, invstd);
  spike_kernel<uint8_t><<<spikeBlocks, blk, 0, stream>>>(h64, v_g, v_b, mean, invstd, Sv);
  // --- attention (exact integer path) ---
  attn_kernel<<<TB_ * H_, blk, 0, stream>>>(Sq, Sk, Sv, Sbuf);
  // --- proj ---
  conv_gemm<uint8_t><<<gridG, blk, 0, stream>>>(p_w, Sbuf, h64);
  stats_kernel<<<C_, blk, 0, stream>>>(h64, mean, invstd);
  spike_kernel<float><<<spikeBlocks, blk, 0, stream>>>(h64, p_g, p_b, mean, invstd, out);
}

// Round 3
// 1001.894 us; speedup vs baseline: 1.4641x; 1.4641x over previous
//
#include <hip/hip_runtime.h>
#include <stdint.h>
#include <math.h>

// Problem dims
#define T_ 4
#define B_ 8
#define C_ 256
#define N_ 2048
#define TB_ 32          // T_*B_
#define H_ 16
#define D_ 16
#define NTOT 65536      // T_*B_*N_  (BN reduction count per channel)
#define EPS 1e-5
#define NSLOT 1024      // per-channel partial-stat slots = n_blocks(32) * tb(32)

typedef double v4d __attribute__((ext_vector_type(4)));

// ---------------------------------------------------------------------------
// X-tile loader: float input (x, y) or uint8 input (binary spikes s)
// ---------------------------------------------------------------------------
template <typename XT>
__device__ inline float4 load_x4(const XT* p);
template <>
__device__ inline float4 load_x4<float>(const float* p) { return *(const float4*)p; }
template <>
__device__ inline float4 load_x4<uint8_t>(const uint8_t* p) {
  uchar4 u = *(const uchar4*)p;
  return make_float4((float)u.x, (float)u.y, (float)u.z, (float)u.w);
}

// ---------------------------------------------------------------------------
// conv1x1 GEMM, fp64 accumulation on the MATRIX pipe (v_mfma_f64_16x16x4_f64).
//   H[tb][o][n] = sum_c W[o][c] * X[tb][c][n]
// fp32 products are exact in fp64; MFMA-f64 is a true fp64 FMA accumulate.
//
// A/B input layout (universal CDNA 16x16 convention): A[m][k] m=lane&15,
// k=lane>>4; B[k][n] n=lane&15, k=lane>>4.
// D layout is probed AT RUNTIME: p1 = mfma(a=lane_id, b=1, 0) yields, at
// (lane, reg), the value sum_k A[row][k] = 4*row + 96 — decoding `row`
// without assuming how regs map to rows (handles both row=4*(lane>>4)+reg
// and the interleaved row=(lane>>4)+4*reg candidates; col=lane&15 in both).
//
// Epilogue: store H + per-channel (sum,sumsq) partials (indexed, no atomics).
// ---------------------------------------------------------------------------
template <typename XT>
__global__ __launch_bounds__(256) void conv_gemm_mfma(const float* __restrict__ W,
                                                      const XT* __restrict__ X,
                                                      double* __restrict__ Hout,
                                                      double* __restrict__ Psum,
                                                      double* __restrict__ Psq) {
  __shared__ float Ws[16][80];   // [k][o]  (stride 80: 2-way bank alias = free)
  __shared__ float Xs[16][80];   // [k][n]
  const int n0 = blockIdx.x * 64;
  const int o0 = blockIdx.y * 64;
  const int tb = blockIdx.z;
  const int tid = (int)threadIdx.x;
  const int wv = tid >> 6;       // wave 0..3
  const int lane = tid & 63;
  const int l15 = lane & 15;
  const int g = lane >> 4;       // k-group 0..3

  // ---- runtime D-layout probe ----
  int rowmap[4];
  {
    v4d p1 = (v4d){0.0, 0.0, 0.0, 0.0};
    p1 = __builtin_amdgcn_mfma_f64_16x16x4f64((double)lane, 1.0, p1, 0, 0, 0);
#pragma unroll
    for (int r = 0; r < 4; ++r) {
      int rm = (int)((p1[r] - 96.0) * 0.25 + 0.5);
      rowmap[r] = rm < 0 ? 0 : (rm > 15 ? 15 : rm);
    }
  }

  // staging indices
  const int aw_o = tid >> 2;           // 0..63 (o row for W load)
  const int aw_c = (tid & 3) * 4;      // c offset (float4 along c)
  const int bx_c = tid >> 4;           // 0..15 (c row for X load)
  const int bx_n = (tid & 15) * 4;     // n offset (float4 along n)

  v4d acc[4];
#pragma unroll
  for (int t = 0; t < 4; ++t) acc[t] = (v4d){0.0, 0.0, 0.0, 0.0};

  for (int c0 = 0; c0 < C_; c0 += 16) {
    const float4 w4 = *(const float4*)(W + (size_t)(o0 + aw_o) * C_ + c0 + aw_c);
    const float4 xv = load_x4<XT>(X + ((size_t)(tb * C_ + c0 + bx_c)) * N_ + n0 + bx_n);
    __syncthreads();  // previous iteration's LDS reads done
    Ws[aw_c + 0][aw_o] = w4.x;
    Ws[aw_c + 1][aw_o] = w4.y;
    Ws[aw_c + 2][aw_o] = w4.z;
    Ws[aw_c + 3][aw_o] = w4.w;
    *(float4*)&Xs[bx_c][bx_n] = xv;
    __syncthreads();
#pragma unroll
    for (int kk = 0; kk < 4; ++kk) {
      const double a = (double)Ws[kk * 4 + g][16 * wv + l15];
#pragma unroll
      for (int t = 0; t < 4; ++t) {
        const double b = (double)Xs[kk * 4 + g][16 * t + l15];
        acc[t] = __builtin_amdgcn_mfma_f64_16x16x4f64(a, b, acc[t], 0, 0, 0);
      }
    }
  }

  // ---- epilogue: store H, accumulate per-channel partial stats ----
  double s[4] = {0.0, 0.0, 0.0, 0.0};
  double q[4] = {0.0, 0.0, 0.0, 0.0};
#pragma unroll
  for (int t = 0; t < 4; ++t) {
#pragma unroll
    for (int r = 0; r < 4; ++r) {
      const double v = acc[t][r];
      const int row = o0 + 16 * wv + rowmap[r];
      Hout[((size_t)(tb * C_ + row)) * N_ + n0 + 16 * t + l15] = v;
      s[r] += v;
      q[r] += v * v;
    }
  }
  // butterfly over low 4 lane bits: rowmap is uniform within a k-group, so
  // this sums the full 64 columns for each of the group's 4 rows.
#pragma unroll
  for (int m = 1; m < 16; m <<= 1) {
#pragma unroll
    for (int r = 0; r < 4; ++r) {
      s[r] += __shfl_xor(s[r], m);
      q[r] += __shfl_xor(q[r], m);
    }
  }
  if (l15 < 4) {
    const int r = l15;
    const int c = o0 + 16 * wv + rowmap[r];
    const int slot = tb * 32 + (int)blockIdx.x;
    Psum[(size_t)c * NSLOT + slot] = s[r];
    Psq[(size_t)c * NSLOT + slot] = q[r];
  }
}

// ---------------------------------------------------------------------------
// Finalize BN stats: one block per channel, reduce NSLOT partials (fp64).
// ---------------------------------------------------------------------------
__global__ __launch_bounds__(256) void finalize_stats(const double* __restrict__ Psum,
                                                      const double* __restrict__ Psq,
                                                      double* __restrict__ mean,
                                                      double* __restrict__ invstd) {
  const int c = blockIdx.x;
  const int tid = (int)threadIdx.x;
  double s = 0.0, q = 0.0;
  for (int i = tid; i < NSLOT; i += 256) {
    s += Psum[(size_t)c * NSLOT + i];
    q += Psq[(size_t)c * NSLOT + i];
  }
#pragma unroll
  for (int m = 1; m < 64; m <<= 1) {
    s += __shfl_xor(s, m);
    q += __shfl_xor(q, m);
  }
  __shared__ double ls[4], lq[4];
  if ((tid & 63) == 0) {
    ls[tid >> 6] = s;
    lq[tid >> 6] = q;
  }
  __syncthreads();
  if (tid == 0) {
    const double S = ls[0] + ls[1] + ls[2] + ls[3];
    const double Q = lq[0] + lq[1] + lq[2] + lq[3];
    const double m = S / (double)NTOT;
    const double var = Q / (double)NTOT - m * m;
    mean[c] = m;
    invstd[c] = 1.0 / sqrt(var + EPS);
  }
}

// ---------------------------------------------------------------------------
// BN-normalize + spike (>= 1.0), 8 elements per thread.
// OT = uint8_t (intermediate spike maps) or float (final output).
// ---------------------------------------------------------------------------
template <typename OT>
__device__ inline void store8(OT* p, const int* sp);
template <>
__device__ inline void store8<uint8_t>(uint8_t* p, const int* sp) {
  uint64_t w = 0;
#pragma unroll
  for (int j = 0; j < 8; ++j) w |= ((uint64_t)(uint8_t)sp[j]) << (8 * j);
  *(uint64_t*)p = w;
}
template <>
__device__ inline void store8<float>(float* p, const int* sp) {
  float4 a = make_float4((float)sp[0], (float)sp[1], (float)sp[2], (float)sp[3]);
  float4 b = make_float4((float)sp[4], (float)sp[5], (float)sp[6], (float)sp[7]);
  *(float4*)p = a;
  *(float4*)(p + 4) = b;
}

template <typename OT>
__global__ __launch_bounds__(256) void spike_kernel(const double* __restrict__ Hh,
                                                    const float* __restrict__ gamma,
                                                    const float* __restrict__ beta,
                                                    const double* __restrict__ mean,
                                                    const double* __restrict__ invstd,
                                                    OT* __restrict__ out) {
  const size_t i0 = ((size_t)blockIdx.x * 256 + threadIdx.x) * 8;
  const int c = (int)((i0 >> 11) & 255);  // N_=2048 -> 8 consecutive share channel
  const double gm = (double)gamma[c];
  const double bt = (double)beta[c];
  const double mu = mean[c];
  const double is = invstd[c];
  int sp[8];
#pragma unroll
  for (int j = 0; j < 8; ++j) {
    const double v = gm * (Hh[i0 + j] - mu) * is + bt;
    sp[j] = (v >= 1.0) ? 1 : 0;
  }
  store8<OT>(out + i0, sp);
}

// ---------------------------------------------------------------------------
// Linear attention, all-binary operands -> exact integer arithmetic.
// ---------------------------------------------------------------------------
__global__ __launch_bounds__(256) void attn_kernel(const uint8_t* __restrict__ Sq,
                                                   const uint8_t* __restrict__ Sk,
                                                   const uint8_t* __restrict__ Sv,
                                                   uint8_t* __restrict__ Sout) {
  __shared__ float kvs[16][17];
  const int tb = (int)blockIdx.x >> 4;
  const int h = (int)blockIdx.x & 15;
  const size_t base = ((size_t)(tb * C_ + h * D_)) * N_;
  const int tid = (int)threadIdx.x;
  {
    const int d = tid >> 4, e = tid & 15;
    const uint32_t* kr = (const uint32_t*)(Sk + base + (size_t)d * N_);
    const uint32_t* vr = (const uint32_t*)(Sv + base + (size_t)e * N_);
    int cnt = 0;
    for (int i = 0; i < N_ / 4; ++i) cnt += __popc(kr[i] & vr[i]);
    kvs[d][e] = (float)cnt;
  }
  __syncthreads();
  for (int rep = 0; rep < 8; ++rep) {
    const int n = rep * 256 + tid;
    float qv[16];
#pragma unroll
    for (int d = 0; d < 16; ++d) qv[d] = (float)Sq[base + (size_t)d * N_ + n];
#pragma unroll
    for (int e = 0; e < 16; ++e) {
      float acc = 0.f;
#pragma unroll
      for (int d = 0; d < 16; ++d) acc += qv[d] * kvs[d][e];
      Sout[base + (size_t)e * N_ + n] = (0.25f * acc >= 0.5f) ? (uint8_t)1 : (uint8_t)0;
    }
  }
}

// ---------------------------------------------------------------------------
// Launcher. ws layout (bytes) — max offset 192 MB (round-1-proven footprint):
//   [0, 128M)       h64 double[16M] (reused by all 4 convs)
//   [128M, 144M)    Sq u8[16M]
//   [144M, 160M)    Sk u8[16M]
//   [160M, 176M)    Sv u8[16M]
//   [176M, 192M)    Sbuf u8[16M]
// Stats scratch (2M+2M+2K+2K = ~4.004M) is OVERLAID in dead regions:
//   Q/K/V stages -> inside Sbuf's region (Sbuf is only written later by attn)
//   proj stage   -> inside Sq's region  (Sq is dead after attn)
// ---------------------------------------------------------------------------
extern "C" void kernel_launch(void* const* d_in, const int* in_sizes, int n_in,
                              void* d_out, int out_size, void* d_ws, size_t ws_size,
                              hipStream_t stream) {
  const float* x   = (const float*)d_in[0];
  const float* y   = (const float*)d_in[1];
  const float* q_w = (const float*)d_in[2];
  const float* q_g = (const float*)d_in[3];
  const float* q_b = (const float*)d_in[4];
  const float* k_w = (const float*)d_in[5];
  const float* k_g = (const float*)d_in[6];
  const float* k_b = (const float*)d_in[7];
  const float* v_w = (const float*)d_in[8];
  const float* v_g = (const float*)d_in[9];
  const float* v_b = (const float*)d_in[10];
  const float* p_w = (const float*)d_in[11];
  const float* p_g = (const float*)d_in[12];
  const float* p_b = (const float*)d_in[13];
  float* out = (float*)d_out;

  char* ws = (char*)d_ws;
  const size_t NE = (size_t)TB_ * C_ * N_;  // 16,777,216
  double* h64   = (double*)ws;
  uint8_t* Sq   = (uint8_t*)(ws + NE * 8);
  uint8_t* Sk   = Sq + NE;
  uint8_t* Sv   = Sk + NE;
  uint8_t* Sbuf = Sv + NE;

  // stats scratch A: overlaid at start of Sbuf region (Q/K/V stages)
  double* PsumA   = (double*)Sbuf;
  double* PsqA    = PsumA + (size_t)C_ * NSLOT;
  double* meanA   = PsqA + (size_t)C_ * NSLOT;
  double* invstdA = meanA + C_;
  // stats scratch B: overlaid at start of Sq region (proj stage)
  double* PsumB   = (double*)Sq;
  double* PsqB    = PsumB + (size_t)C_ * NSLOT;
  double* meanB   = PsqB + (size_t)C_ * NSLOT;
  double* invstdB = meanB + C_;

  const dim3 gridG(N_ / 64, C_ / 64, TB_);  // 32,4,32
  const dim3 blk(256);
  const int spikeBlocks = (int)(NE / (256 * 8));  // 8192

  // --- Q from x ---
  conv_gemm_mfma<float><<<gridG, blk, 0, stream>>>(q_w, x, h64, PsumA, PsqA);
  finalize_stats<<<C_, blk, 0, stream>>>(PsumA, PsqA, meanA, invstdA);
  spike_kernel<uint8_t><<<spikeBlocks, blk, 0, stream>>>(h64, q_g, q_b, meanA, invstdA, Sq);
  // --- K from y ---
  conv_gemm_mfma<float><<<gridG, blk, 0, stream>>>(k_w, y, h64, PsumA, PsqA);
  finalize_stats<<<C_, blk, 0, stream>>>(PsumA, PsqA, meanA, invstdA);
  spike_kernel<uint8_t><<<spikeBlocks, blk, 0, stream>>>(h64, k_g, k_b, meanA, invstdA, Sk);
  // --- V from y ---
  conv_gemm_mfma<float><<<gridG, blk, 0, stream>>>(v_w, y, h64, PsumA, PsqA);
  finalize_stats<<<C_, blk, 0, stream>>>(PsumA, PsqA, meanA, invstdA);
  spike_kernel<uint8_t><<<spikeBlocks, blk, 0, stream>>>(h64, v_g, v_b, meanA, invstdA, Sv);
  // --- attention (exact integer path; overwrites stats scratch A = fine) ---
  attn_kernel<<<TB_ * H_, blk, 0, stream>>>(Sq, Sk, Sv, Sbuf);
  // --- proj (stats scratch B lives in Sq's region, dead after attn) ---
  conv_gemm_mfma<uint8_t><<<gridG, blk, 0, stream>>>(p_w, Sbuf, h64, PsumB, PsqB);
  finalize_stats<<<C_, blk, 0, stream>>>(PsumB, PsqB, meanB, invstdB);
  spike_kernel<float><<<spikeBlocks, blk, 0, stream>>>(h64, p_g, p_b, meanB, invstdB, out);
}